// Round 1
// baseline (584.585 us; speedup 1.0000x reference)
//
#include <hip/hip_runtime.h>
#include <hip/hip_bf16.h>

// Problem constants (from setup_inputs): B=4, S=2048, D_IN=2048, D_OUT=2048
constexpr int D_IN  = 2048;
constexpr int D_OUT = 2048;
constexpr int GM = 4 * 2048;      // B*S rows
constexpr int GK = 2 * D_IN;      // 4096 (concat real|imag)
constexpr int GN = 2 * D_OUT;     // 4096 (concat y_real|y_imag channels)

typedef __attribute__((ext_vector_type(8))) short bf16x8;
typedef __attribute__((ext_vector_type(4))) float f32x4;

constexpr int QB = 1024;          // quant kernel blocks

// Exact bf16 bit patterns for {0, +-0.5, +-1}; negate = XOR 0x8000.
__device__ inline unsigned short q4bits(float w) {
    if (w >  0.75f) return 0x3F80;   // 1.0
    if (w >  0.25f) return 0x3F00;   // 0.5
    if (w < -0.75f) return 0xBF80;   // -1.0
    if (w < -0.25f) return 0xBF00;   // -0.5
    return 0;
}

__device__ inline unsigned short bf16b(float x) {
    __hip_bfloat16 h = __float2bfloat16(x);
    unsigned short u;
    __builtin_memcpy(&u, &h, 2);
    return u;
}

// ---------------------------------------------------------------------------
// Kernel 1: quantize weights into W_cat (bf16, GN x GK, row-major); block sums
// of |w_re|, |w_im| are accumulated directly into sums[2] via device-scope
// atomics (sums zeroed by hipMemsetAsync before launch) - removes the
// separate reduce kernel from the serial chain.
// W_cat row n<2048:  [ qre[n,:] | -qim[n,:] ]   -> y_real channels
// W_cat row n>=2048: [ qim[n,:] |  qre[n,:] ]   -> y_imag channels
// ---------------------------------------------------------------------------
__global__ __launch_bounds__(256) void quant_kernel(
        const float* __restrict__ wre, const float* __restrict__ wim,
        unsigned short* __restrict__ wq, float* __restrict__ sums) {
    float a = 0.f, b = 0.f;
    int tid = blockIdx.x * 256 + threadIdx.x;     // 0 .. 262143
    const float4* wre4 = (const float4*)wre;
    const float4* wim4 = (const float4*)wim;
    for (int c = 0; c < 4; c++) {
        int f4i = tid + c * (QB * 256);           // float4 index, coalesced
        int idx = f4i * 4;
        int o = idx >> 11;                        // row in D_OUT
        int k = idx & (D_IN - 1);                 // col in D_IN (multiple of 4)
        float4 r = wre4[f4i];
        float4 im = wim4[f4i];
        a += fabsf(r.x) + fabsf(r.y) + fabsf(r.z) + fabsf(r.w);
        b += fabsf(im.x) + fabsf(im.y) + fabsf(im.z) + fabsf(im.w);
        ushort4 qre, qim, nim;
        qre.x = q4bits(r.x);  qre.y = q4bits(r.y);  qre.z = q4bits(r.z);  qre.w = q4bits(r.w);
        qim.x = q4bits(im.x); qim.y = q4bits(im.y); qim.z = q4bits(im.z); qim.w = q4bits(im.w);
        nim.x = qim.x ^ 0x8000; nim.y = qim.y ^ 0x8000;
        nim.z = qim.z ^ 0x8000; nim.w = qim.w ^ 0x8000;
        *(ushort4*)(wq + (size_t)o * GK + k)                  = qre;
        *(ushort4*)(wq + (size_t)o * GK + D_IN + k)           = nim;
        *(ushort4*)(wq + (size_t)(D_OUT + o) * GK + k)        = qim;
        *(ushort4*)(wq + (size_t)(D_OUT + o) * GK + D_IN + k) = qre;
    }
    for (int off = 32; off; off >>= 1) {
        a += __shfl_down(a, off, 64);
        b += __shfl_down(b, off, 64);
    }
    __shared__ float sa[4], sb[4];
    int lane = threadIdx.x & 63, wv = threadIdx.x >> 6;
    if (lane == 0) { sa[wv] = a; sb[wv] = b; }
    __syncthreads();
    if (threadIdx.x == 0) {
        atomicAdd(&sums[0], sa[0] + sa[1] + sa[2] + sa[3]);
        atomicAdd(&sums[1], sb[0] + sb[1] + sb[2] + sb[3]);
    }
}

// ---------------------------------------------------------------------------
// Kernel 2: LayerNorm over concat row [x_real[m,:], x_imag[m,:]] (4096 elems),
// writes bf16 activations A (GM x GK row-major). One 256-thread block per row.
// ---------------------------------------------------------------------------
__global__ __launch_bounds__(256) void ln_kernel(
        const float* __restrict__ xr, const float* __restrict__ xi,
        const float* __restrict__ gamma, const float* __restrict__ beta,
        unsigned short* __restrict__ A) {
    int m = blockIdx.x;
    int t = threadIdx.x;
    const float4* r4 = (const float4*)(xr + (size_t)m * D_IN);
    const float4* i4 = (const float4*)(xi + (size_t)m * D_IN);
    float4 vr[2], vi[2];
    float s = 0.f, ss = 0.f;
    for (int c = 0; c < 2; c++) {
        float4 v = r4[t + c * 256];
        vr[c] = v;
        s  += v.x + v.y + v.z + v.w;
        ss += v.x * v.x + v.y * v.y + v.z * v.z + v.w * v.w;
        v = i4[t + c * 256];
        vi[c] = v;
        s  += v.x + v.y + v.z + v.w;
        ss += v.x * v.x + v.y * v.y + v.z * v.z + v.w * v.w;
    }
    for (int off = 32; off; off >>= 1) {
        s  += __shfl_down(s, off, 64);
        ss += __shfl_down(ss, off, 64);
    }
    __shared__ float red[8];
    __shared__ float smu, srs;
    int lane = t & 63, wv = t >> 6;
    if (lane == 0) { red[wv] = s; red[4 + wv] = ss; }
    __syncthreads();
    if (t == 0) {
        float S  = red[0] + red[1] + red[2] + red[3];
        float SS = red[4] + red[5] + red[6] + red[7];
        float mu  = S * (1.0f / 4096.0f);
        float var = SS * (1.0f / 4096.0f) - mu * mu;
        smu = mu;
        srs = rsqrtf(var + 1e-6f);
    }
    __syncthreads();
    float mu = smu, rs = srs;
    const float4* g4 = (const float4*)gamma;
    const float4* b4 = (const float4*)beta;
    ushort4* Arow = (ushort4*)(A + (size_t)m * GK);
    for (int c = 0; c < 2; c++) {
        int k4 = t + c * 256;                 // float4 index in real half
        float4 g = g4[k4], b = b4[k4];
        float4 v = vr[c];
        ushort4 o;
        o.x = bf16b((v.x - mu) * rs * g.x + b.x);
        o.y = bf16b((v.y - mu) * rs * g.y + b.y);
        o.z = bf16b((v.z - mu) * rs * g.z + b.z);
        o.w = bf16b((v.w - mu) * rs * g.w + b.w);
        Arow[k4] = o;
        g = g4[512 + k4]; b = b4[512 + k4];
        v = vi[c];
        o.x = bf16b((v.x - mu) * rs * g.x + b.x);
        o.y = bf16b((v.y - mu) * rs * g.y + b.y);
        o.z = bf16b((v.z - mu) * rs * g.z + b.z);
        o.w = bf16b((v.w - mu) * rs * g.w + b.w);
        Arow[512 + k4] = o;
    }
}

// ---------------------------------------------------------------------------
// Kernel 3: GEMM  Y(GM x GN) = A(GM x GK) * W_cat^T, W_cat stored N x K.
//
// 256x256 tile, BK=64, 8 waves (2M x 4N), per-wave 128x64 C = acc[8][4].
// Double-buffered LDS (128 KiB), 4 phases per K-tile:
//   phase = { ds_read quadrant frags | issue 2 global_load_lds of NEXT tile
//             -> s_barrier -> lgkmcnt(0)+sched_barrier -> setprio(1),
//             16 MFMA, setprio(0) -> s_barrier }
// Counted vmcnt(2) once per K-tile (tail: vmcnt(0)) - next tile's first 2
// loads stay in flight across the wait; raw s_barrier (NOT __syncthreads)
// so the compiler never drains vmcnt at barriers.
//
// LDS is XOR-swizzled exactly as the verified 128^2 kernel: physical 16B
// chunk p of row rr holds logical chunk p ^ (rr&7); staging lanes fetch
// global chunk (lane&7)^(lane>>3) so the hardware's lane-contiguous LDS
// placement realizes the swizzle (conflict-free ds_read_b128, measured 0).
//
// Race safety: all mid-tile stages write the non-compute buffer; phase-0
// stage of tile kt+1 writes buf[kt+1 & 1] != buf[kt & 1]; every wave's
// reads of a buffer retire at its own lgkmcnt(0) before its phase-3 end
// barrier, so cross-iteration stage issues (pinned below the previous
// barrier by the phase-0 sched_barrier + memory-clobber waitcnt asm) can
// never overwrite data still being read.
// ---------------------------------------------------------------------------
__global__ __launch_bounds__(512, 2) void gemm_kernel(
        const unsigned short* __restrict__ A,
        const unsigned short* __restrict__ Wq,
        const float* __restrict__ sums,
        float* __restrict__ out) {
    constexpr int BM = 256, BN = 256, BK = 64;
    constexpr int NT = GK / BK;                  // 64 K-tiles
    __shared__ unsigned short shA[2][BM * BK];   // 2 x 32 KiB
    __shared__ unsigned short shB[2][BN * BK];   // 2 x 32 KiB

    // XCD-bijective block swizzle: 512 blocks, 512 % 8 == 0 -> simple form ok.
    int lin = blockIdx.y * gridDim.x + blockIdx.x;       // 0..511
    int swz = (lin & 7) * 64 + (lin >> 3);
    int m0 = (swz >> 4) * BM;                            // 32 M-tiles
    int n0 = (swz & 15) * BN;                            // 16 N-tiles

    int t = threadIdx.x;
    int lane = t & 63, wid = t >> 6;         // 8 waves
    int wr = wid >> 2, wc = wid & 3;         // 2 x 4 wave grid
    int quad = lane >> 4, r = lane & 15;
    int srow = lane >> 3;                    // staging: row within 8-row group
    int scol = ((lane & 7) ^ srow) * 8;      // staging: swizzled bf16 col
    int csw0 = (quad ^ (r & 7)) * 8;         // reader: elem offset at ks=0

    int aRow0 = (wr * 128 + r) * BK;         // element offsets into LDS
    int bRow0 = (wc * 64 + r) * BK;

    f32x4 acc[8][4] = {};
    bf16x8 a[4][2], b[2][2];

#define STAGE(mm, bb, kk, ss) do {                                             \
        int dstRow = wid * 32 + (ss) * 8;                                      \
        const unsigned short* gsrc =                                           \
            ((mm) ? Wq + (size_t)(n0 + dstRow + srow) * GK                     \
                  : A  + (size_t)(m0 + dstRow + srow) * GK)                    \
            + (kk) * BK + scol;                                                \
        unsigned short* lp = ((mm) ? shB[bb] : shA[bb]) + dstRow * BK;         \
        __builtin_amdgcn_global_load_lds(                                      \
            (const __attribute__((address_space(1))) void*)(const void*)gsrc,  \
            (__attribute__((address_space(3))) void*)(void*)lp, 16, 0, 0);     \
    } while (0)

#define READ_A(mh) do {                                                        \
        const short* pa_ = (const short*)shA[cur];                             \
        _Pragma("unroll") for (int im = 0; im < 4; ++im)                       \
        _Pragma("unroll") for (int ks = 0; ks < 2; ++ks)                       \
            a[im][ks] = *(const bf16x8*)(pa_ + aRow0                           \
                + ((mh) * 4 + im) * (16 * BK) + (csw0 ^ (ks * 32)));           \
    } while (0)

#define READ_B(nh) do {                                                        \
        const short* pb_ = (const short*)shB[cur];                             \
        _Pragma("unroll") for (int jn = 0; jn < 2; ++jn)                       \
        _Pragma("unroll") for (int ks = 0; ks < 2; ++ks)                       \
            b[jn][ks] = *(const bf16x8*)(pb_ + bRow0                           \
                + ((nh) * 2 + jn) * (16 * BK) + (csw0 ^ (ks * 32)));           \
    } while (0)

#define MFMA_Q(mh, nh) do {                                                    \
        __builtin_amdgcn_s_setprio(1);                                         \
        _Pragma("unroll") for (int im = 0; im < 4; ++im)                       \
        _Pragma("unroll") for (int jn = 0; jn < 2; ++jn)                       \
        _Pragma("unroll") for (int ks = 0; ks < 2; ++ks)                       \
            acc[(mh) * 4 + im][(nh) * 2 + jn] =                                \
                __builtin_amdgcn_mfma_f32_16x16x32_bf16(                       \
                    a[im][ks], b[jn][ks],                                      \
                    acc[(mh) * 4 + im][(nh) * 2 + jn], 0, 0, 0);               \
        __builtin_amdgcn_s_setprio(0);                                         \
    } while (0)

    // Prologue: stage tile 0 into buf 0 (8 issues/wave; covered rows:
    // wid*32 + ss*8 + srow over 8 waves x 4 issues x 8 lanesets = 0..255).
    #pragma unroll
    for (int ss = 0; ss < 4; ++ss) STAGE(0, 0, 0, ss);
    #pragma unroll
    for (int ss = 0; ss < 4; ++ss) STAGE(1, 0, 0, ss);

    #pragma unroll 2
    for (int kt = 0; kt < NT; ++kt) {
        int cur = kt & 1, nxt = cur ^ 1;
        bool more = (kt < NT - 1);

        // ---- phase 0: quadrant (0,0); tile-boundary counted wait ----
        __builtin_amdgcn_sched_barrier(0);   // pin stages below prev barrier
        if (more) { STAGE(0, nxt, kt + 1, 0); STAGE(0, nxt, kt + 1, 1); }
        if (more) asm volatile("s_waitcnt vmcnt(2)" ::: "memory");
        else      asm volatile("s_waitcnt vmcnt(0)" ::: "memory");
        __builtin_amdgcn_s_barrier();        // tile kt fully landed, all waves
        __builtin_amdgcn_sched_barrier(0);
        READ_A(0); READ_B(0);
        asm volatile("s_waitcnt lgkmcnt(0)" ::: "memory");
        __builtin_amdgcn_sched_barrier(0);
        MFMA_Q(0, 0);
        __builtin_amdgcn_s_barrier();

        // ---- phase 1: quadrant (0,1), reuse a ----
        READ_B(1);
        if (more) { STAGE(0, nxt, kt + 1, 2); STAGE(0, nxt, kt + 1, 3); }
        __builtin_amdgcn_s_barrier();
        asm volatile("s_waitcnt lgkmcnt(0)" ::: "memory");
        __builtin_amdgcn_sched_barrier(0);
        MFMA_Q(0, 1);
        __builtin_amdgcn_s_barrier();

        // ---- phase 2: quadrant (1,1), reuse b ----
        READ_A(1);
        if (more) { STAGE(1, nxt, kt + 1, 0); STAGE(1, nxt, kt + 1, 1); }
        __builtin_amdgcn_s_barrier();
        asm volatile("s_waitcnt lgkmcnt(0)" ::: "memory");
        __builtin_amdgcn_sched_barrier(0);
        MFMA_Q(1, 1);
        __builtin_amdgcn_s_barrier();

        // ---- phase 3: quadrant (1,0), reuse a ----
        READ_B(0);
        if (more) { STAGE(1, nxt, kt + 1, 2); STAGE(1, nxt, kt + 1, 3); }
        __builtin_amdgcn_s_barrier();
        asm volatile("s_waitcnt lgkmcnt(0)" ::: "memory");
        __builtin_amdgcn_sched_barrier(0);
        MFMA_Q(1, 0);
        __builtin_amdgcn_s_barrier();
    }

#undef STAGE
#undef READ_A
#undef READ_B
#undef MFMA_Q

    // Epilogue: per-block uniform half selection (BN=256 divides D_OUT)
    float s_re = sums[0] * (1.0f / (2048.0f * 2048.0f));
    float s_im = sums[1] * (1.0f / (2048.0f * 2048.0f));
    float scale;
    float* obase;
    int ncol0;
    if (n0 < D_OUT) { scale = s_re; obase = out;                      ncol0 = n0; }
    else            { scale = s_im; obase = out + (size_t)GM * D_OUT; ncol0 = n0 - D_OUT; }

    #pragma unroll
    for (int f = 0; f < 8; ++f)
        #pragma unroll
        for (int g = 0; g < 4; ++g) {
            int mrow = m0 + wr * 128 + f * 16 + quad * 4;  // row=(lane>>4)*4+reg
            int ncol = ncol0 + wc * 64 + g * 16 + r;       // col=lane&15
            #pragma unroll
            for (int reg = 0; reg < 4; ++reg)
                obase[(size_t)(mrow + reg) * D_OUT + ncol] = acc[f][g][reg] * scale;
        }
}

extern "C" void kernel_launch(void* const* d_in, const int* in_sizes, int n_in,
                              void* d_out, int out_size, void* d_ws, size_t ws_size,
                              hipStream_t stream) {
    const float* xr    = (const float*)d_in[0];
    const float* xi    = (const float*)d_in[1];
    const float* wre   = (const float*)d_in[2];
    const float* wim   = (const float*)d_in[3];
    const float* gamma = (const float*)d_in[4];
    const float* beta  = (const float*)d_in[5];
    float* out = (float*)d_out;

    // ws layout: A bf16 (GM*GK), W_cat bf16 (GN*GK), sums (2 f32)
    unsigned short* A  = (unsigned short*)d_ws;
    unsigned short* Wq = (unsigned short*)((char*)d_ws + (size_t)GM * GK * 2);
    float* sums = (float*)((char*)d_ws + (size_t)GM * GK * 2 + (size_t)GN * GK * 2);

    (void)hipMemsetAsync(sums, 0, 2 * sizeof(float), stream);
    quant_kernel<<<QB, 256, 0, stream>>>(wre, wim, Wq, sums);
    ln_kernel<<<GM, 256, 0, stream>>>(xr, xi, gamma, beta, A);
    gemm_kernel<<<dim3(GN / 256, GM / 256), 512, 0, stream>>>(A, Wq, sums, out);
}

// Round 2
// 566.035 us; speedup vs baseline: 1.0328x; 1.0328x over previous
//
#include <hip/hip_runtime.h>
#include <hip/hip_bf16.h>

// Problem constants (from setup_inputs): B=4, S=2048, D_IN=2048, D_OUT=2048
constexpr int D_IN  = 2048;
constexpr int D_OUT = 2048;
constexpr int GM = 4 * 2048;      // B*S rows
constexpr int GK = 2 * D_IN;      // 4096 (concat real|imag)
constexpr int GN = 2 * D_OUT;     // 4096 (concat y_real|y_imag channels)

typedef __attribute__((ext_vector_type(8))) short bf16x8;
typedef __attribute__((ext_vector_type(4))) float f32x4;

constexpr int QB = 1024;          // quant kernel blocks

// Exact bf16 bit patterns for {0, +-0.5, +-1}; negate = XOR 0x8000.
__device__ inline unsigned short q4bits(float w) {
    if (w >  0.75f) return 0x3F80;   // 1.0
    if (w >  0.25f) return 0x3F00;   // 0.5
    if (w < -0.75f) return 0xBF80;   // -1.0
    if (w < -0.25f) return 0xBF00;   // -0.5
    return 0;
}

__device__ inline unsigned short bf16b(float x) {
    __hip_bfloat16 h = __float2bfloat16(x);
    unsigned short u;
    __builtin_memcpy(&u, &h, 2);
    return u;
}

// ---------------------------------------------------------------------------
// Kernel 1: quantize weights into W_cat (bf16, GN x GK, row-major); block sums
// of |w_re|, |w_im| accumulated into sums[2] via device-scope atomics
// (sums zeroed by hipMemsetAsync before launch).
// W_cat row n<2048:  [ qre[n,:] | -qim[n,:] ]   -> y_real channels
// W_cat row n>=2048: [ qim[n,:] |  qre[n,:] ]   -> y_imag channels
// ---------------------------------------------------------------------------
__global__ __launch_bounds__(256) void quant_kernel(
        const float* __restrict__ wre, const float* __restrict__ wim,
        unsigned short* __restrict__ wq, float* __restrict__ sums) {
    float a = 0.f, b = 0.f;
    int tid = blockIdx.x * 256 + threadIdx.x;     // 0 .. 262143
    const float4* wre4 = (const float4*)wre;
    const float4* wim4 = (const float4*)wim;
    for (int c = 0; c < 4; c++) {
        int f4i = tid + c * (QB * 256);           // float4 index, coalesced
        int idx = f4i * 4;
        int o = idx >> 11;                        // row in D_OUT
        int k = idx & (D_IN - 1);                 // col in D_IN (multiple of 4)
        float4 r = wre4[f4i];
        float4 im = wim4[f4i];
        a += fabsf(r.x) + fabsf(r.y) + fabsf(r.z) + fabsf(r.w);
        b += fabsf(im.x) + fabsf(im.y) + fabsf(im.z) + fabsf(im.w);
        ushort4 qre, qim, nim;
        qre.x = q4bits(r.x);  qre.y = q4bits(r.y);  qre.z = q4bits(r.z);  qre.w = q4bits(r.w);
        qim.x = q4bits(im.x); qim.y = q4bits(im.y); qim.z = q4bits(im.z); qim.w = q4bits(im.w);
        nim.x = qim.x ^ 0x8000; nim.y = qim.y ^ 0x8000;
        nim.z = qim.z ^ 0x8000; nim.w = qim.w ^ 0x8000;
        *(ushort4*)(wq + (size_t)o * GK + k)                  = qre;
        *(ushort4*)(wq + (size_t)o * GK + D_IN + k)           = nim;
        *(ushort4*)(wq + (size_t)(D_OUT + o) * GK + k)        = qim;
        *(ushort4*)(wq + (size_t)(D_OUT + o) * GK + D_IN + k) = qre;
    }
    for (int off = 32; off; off >>= 1) {
        a += __shfl_down(a, off, 64);
        b += __shfl_down(b, off, 64);
    }
    __shared__ float sa[4], sb[4];
    int lane = threadIdx.x & 63, wv = threadIdx.x >> 6;
    if (lane == 0) { sa[wv] = a; sb[wv] = b; }
    __syncthreads();
    if (threadIdx.x == 0) {
        atomicAdd(&sums[0], sa[0] + sa[1] + sa[2] + sa[3]);
        atomicAdd(&sums[1], sb[0] + sb[1] + sb[2] + sb[3]);
    }
}

// ---------------------------------------------------------------------------
// Kernel 2: LayerNorm over concat row [x_real[m,:], x_imag[m,:]] (4096 elems),
// writes bf16 activations A (GM x GK row-major). One 256-thread block per row.
// ---------------------------------------------------------------------------
__global__ __launch_bounds__(256) void ln_kernel(
        const float* __restrict__ xr, const float* __restrict__ xi,
        const float* __restrict__ gamma, const float* __restrict__ beta,
        unsigned short* __restrict__ A) {
    int m = blockIdx.x;
    int t = threadIdx.x;
    const float4* r4 = (const float4*)(xr + (size_t)m * D_IN);
    const float4* i4 = (const float4*)(xi + (size_t)m * D_IN);
    float4 vr[2], vi[2];
    float s = 0.f, ss = 0.f;
    for (int c = 0; c < 2; c++) {
        float4 v = r4[t + c * 256];
        vr[c] = v;
        s  += v.x + v.y + v.z + v.w;
        ss += v.x * v.x + v.y * v.y + v.z * v.z + v.w * v.w;
        v = i4[t + c * 256];
        vi[c] = v;
        s  += v.x + v.y + v.z + v.w;
        ss += v.x * v.x + v.y * v.y + v.z * v.z + v.w * v.w;
    }
    for (int off = 32; off; off >>= 1) {
        s  += __shfl_down(s, off, 64);
        ss += __shfl_down(ss, off, 64);
    }
    __shared__ float red[8];
    __shared__ float smu, srs;
    int lane = t & 63, wv = t >> 6;
    if (lane == 0) { red[wv] = s; red[4 + wv] = ss; }
    __syncthreads();
    if (t == 0) {
        float S  = red[0] + red[1] + red[2] + red[3];
        float SS = red[4] + red[5] + red[6] + red[7];
        float mu  = S * (1.0f / 4096.0f);
        float var = SS * (1.0f / 4096.0f) - mu * mu;
        smu = mu;
        srs = rsqrtf(var + 1e-6f);
    }
    __syncthreads();
    float mu = smu, rs = srs;
    const float4* g4 = (const float4*)gamma;
    const float4* b4 = (const float4*)beta;
    ushort4* Arow = (ushort4*)(A + (size_t)m * GK);
    for (int c = 0; c < 2; c++) {
        int k4 = t + c * 256;                 // float4 index in real half
        float4 g = g4[k4], b = b4[k4];
        float4 v = vr[c];
        ushort4 o;
        o.x = bf16b((v.x - mu) * rs * g.x + b.x);
        o.y = bf16b((v.y - mu) * rs * g.y + b.y);
        o.z = bf16b((v.z - mu) * rs * g.z + b.z);
        o.w = bf16b((v.w - mu) * rs * g.w + b.w);
        Arow[k4] = o;
        g = g4[512 + k4]; b = b4[512 + k4];
        v = vi[c];
        o.x = bf16b((v.x - mu) * rs * g.x + b.x);
        o.y = bf16b((v.y - mu) * rs * g.y + b.y);
        o.z = bf16b((v.z - mu) * rs * g.z + b.z);
        o.w = bf16b((v.w - mu) * rs * g.w + b.w);
        Arow[512 + k4] = o;
    }
}

// ---------------------------------------------------------------------------
// Kernel 3: GEMM  Y(GM x GN) = A(GM x GK) * W_cat^T, W_cat stored N x K.
//
// 256x256 tile, BK=64, 8 waves (2M x 4N), per-wave 128x64 C = acc[8][4].
// Double-buffered LDS (128 KiB).
//
// Schedule (fix of round-1 regression): ALL 8 global_load_lds issues for
// tile kt+1 happen at the TOP of tile kt, immediately after the previous
// tile-end barrier. The single counted wait vmcnt(8) at tile top therefore
// waits on loads issued a FULL TILE (~600+ cycles, 64 MFMA + 24 ds_read)
// earlier -- latency fully covered. Round 1 issued the last stages one
// phase (~150 cy) before waiting on them: a full memory-latency stall per
// K-tile (MfmaUtil 34%). vmcnt never drains to 0 in the main loop (the 8
// next-tile loads stay in flight across the wait).
//
// Per K-tile, 4 phases (one C-quadrant x K=64 each), m201 pattern:
//   { ds_read quadrant frags -> s_barrier -> lgkmcnt(0)+sched_barrier ->
//     setprio(1), 16 MFMA, setprio(0) -> s_barrier }
//
// LDS XOR-swizzle as verified: physical 16B chunk p of row rr holds logical
// chunk p ^ (rr&7); staging lanes fetch global chunk (lane&7)^(lane>>3) so
// the hardware's lane-contiguous LDS placement realizes the swizzle
// (conflict-free ds_read_b128, measured 0).
//
// Race safety: stages into buf nxt are issued after the tile-end barrier of
// tile kt-1 (program order; pinned by sched_barrier(0)); every wave's
// ds_reads of buf nxt during tile kt-1 retired at its own lgkmcnt(0) before
// that barrier, so the DMA writes (which land after issue, after the
// barrier) can never overwrite data still being read.
// ---------------------------------------------------------------------------
__global__ __launch_bounds__(512, 2) void gemm_kernel(
        const unsigned short* __restrict__ A,
        const unsigned short* __restrict__ Wq,
        const float* __restrict__ sums,
        float* __restrict__ out) {
    constexpr int BM = 256, BN = 256, BK = 64;
    constexpr int NT = GK / BK;                  // 64 K-tiles
    __shared__ unsigned short shA[2][BM * BK];   // 2 x 32 KiB
    __shared__ unsigned short shB[2][BN * BK];   // 2 x 32 KiB

    // XCD-bijective block swizzle: 512 blocks, 512 % 8 == 0 -> simple form ok.
    int lin = blockIdx.y * gridDim.x + blockIdx.x;       // 0..511
    int swz = (lin & 7) * 64 + (lin >> 3);
    int m0 = (swz >> 4) * BM;                            // 32 M-tiles
    int n0 = (swz & 15) * BN;                            // 16 N-tiles

    int t = threadIdx.x;
    int lane = t & 63, wid = t >> 6;         // 8 waves
    int wr = wid >> 2, wc = wid & 3;         // 2 x 4 wave grid
    int quad = lane >> 4, r = lane & 15;
    int srow = lane >> 3;                    // staging: row within 8-row group
    int scol = ((lane & 7) ^ srow) * 8;      // staging: swizzled bf16 col
    int csw0 = (quad ^ (r & 7)) * 8;         // reader: elem offset at ks=0

    int aRow0 = (wr * 128 + r) * BK;         // element offsets into LDS
    int bRow0 = (wc * 64 + r) * BK;

    f32x4 acc[8][4] = {};
    bf16x8 a[4][2], b[2][2];

#define STAGE(mm, bb, kk, ss) do {                                             \
        int dstRow = wid * 32 + (ss) * 8;                                      \
        const unsigned short* gsrc =                                           \
            ((mm) ? Wq + (size_t)(n0 + dstRow + srow) * GK                     \
                  : A  + (size_t)(m0 + dstRow + srow) * GK)                    \
            + (kk) * BK + scol;                                                \
        unsigned short* lp = ((mm) ? shB[bb] : shA[bb]) + dstRow * BK;         \
        __builtin_amdgcn_global_load_lds(                                      \
            (const __attribute__((address_space(1))) void*)(const void*)gsrc,  \
            (__attribute__((address_space(3))) void*)(void*)lp, 16, 0, 0);     \
    } while (0)

#define READ_A(mh) do {                                                        \
        const short* pa_ = (const short*)shA[cur];                             \
        _Pragma("unroll") for (int im = 0; im < 4; ++im)                       \
        _Pragma("unroll") for (int ks = 0; ks < 2; ++ks)                       \
            a[im][ks] = *(const bf16x8*)(pa_ + aRow0                           \
                + ((mh) * 4 + im) * (16 * BK) + (csw0 ^ (ks * 32)));           \
    } while (0)

#define READ_B(nh) do {                                                        \
        const short* pb_ = (const short*)shB[cur];                             \
        _Pragma("unroll") for (int jn = 0; jn < 2; ++jn)                       \
        _Pragma("unroll") for (int ks = 0; ks < 2; ++ks)                       \
            b[jn][ks] = *(const bf16x8*)(pb_ + bRow0                           \
                + ((nh) * 2 + jn) * (16 * BK) + (csw0 ^ (ks * 32)));           \
    } while (0)

#define MFMA_Q(mh, nh) do {                                                    \
        __builtin_amdgcn_s_setprio(1);                                         \
        _Pragma("unroll") for (int im = 0; im < 4; ++im)                       \
        _Pragma("unroll") for (int jn = 0; jn < 2; ++jn)                       \
        _Pragma("unroll") for (int ks = 0; ks < 2; ++ks)                       \
            acc[(mh) * 4 + im][(nh) * 2 + jn] =                                \
                __builtin_amdgcn_mfma_f32_16x16x32_bf16(                       \
                    a[im][ks], b[jn][ks],                                      \
                    acc[(mh) * 4 + im][(nh) * 2 + jn], 0, 0, 0);               \
        __builtin_amdgcn_s_setprio(0);                                         \
    } while (0)

    // Prologue: stage tile 0 into buf 0 (8 issues/wave; covered rows:
    // wid*32 + ss*8 + srow over 8 waves x 4 issues x 8 lanesets = 0..255).
    #pragma unroll
    for (int ss = 0; ss < 4; ++ss) STAGE(0, 0, 0, ss);
    #pragma unroll
    for (int ss = 0; ss < 4; ++ss) STAGE(1, 0, 0, ss);

    #pragma unroll 2
    for (int kt = 0; kt < NT; ++kt) {
        int cur = kt & 1, nxt = cur ^ 1;
        bool more = (kt < NT - 1);

        // ---- tile top: issue ALL next-tile stages, then counted wait ----
        __builtin_amdgcn_sched_barrier(0);   // pin stages below prev barrier
        if (more) {
            #pragma unroll
            for (int ss = 0; ss < 4; ++ss) STAGE(0, nxt, kt + 1, ss);
            #pragma unroll
            for (int ss = 0; ss < 4; ++ss) STAGE(1, nxt, kt + 1, ss);
        }
        if (more) asm volatile("s_waitcnt vmcnt(8)" ::: "memory");
        else      asm volatile("s_waitcnt vmcnt(0)" ::: "memory");
        __builtin_amdgcn_s_barrier();        // tile kt fully landed, all waves
        __builtin_amdgcn_sched_barrier(0);

        // ---- phase 0: quadrant (0,0) ----
        READ_A(0); READ_B(0);
        __builtin_amdgcn_s_barrier();
        asm volatile("s_waitcnt lgkmcnt(0)" ::: "memory");
        __builtin_amdgcn_sched_barrier(0);
        MFMA_Q(0, 0);
        __builtin_amdgcn_s_barrier();

        // ---- phase 1: quadrant (0,1), reuse a ----
        READ_B(1);
        __builtin_amdgcn_s_barrier();
        asm volatile("s_waitcnt lgkmcnt(0)" ::: "memory");
        __builtin_amdgcn_sched_barrier(0);
        MFMA_Q(0, 1);
        __builtin_amdgcn_s_barrier();

        // ---- phase 2: quadrant (1,1), reuse b ----
        READ_A(1);
        __builtin_amdgcn_s_barrier();
        asm volatile("s_waitcnt lgkmcnt(0)" ::: "memory");
        __builtin_amdgcn_sched_barrier(0);
        MFMA_Q(1, 1);
        __builtin_amdgcn_s_barrier();

        // ---- phase 3: quadrant (1,0), reuse a ----
        READ_B(0);
        __builtin_amdgcn_s_barrier();
        asm volatile("s_waitcnt lgkmcnt(0)" ::: "memory");
        __builtin_amdgcn_sched_barrier(0);
        MFMA_Q(1, 0);
        __builtin_amdgcn_s_barrier();        // tile-end barrier
    }

#undef STAGE
#undef READ_A
#undef READ_B
#undef MFMA_Q

    // Epilogue: per-block uniform half selection (BN=256 divides D_OUT)
    float s_re = sums[0] * (1.0f / (2048.0f * 2048.0f));
    float s_im = sums[1] * (1.0f / (2048.0f * 2048.0f));
    float scale;
    float* obase;
    int ncol0;
    if (n0 < D_OUT) { scale = s_re; obase = out;                      ncol0 = n0; }
    else            { scale = s_im; obase = out + (size_t)GM * D_OUT; ncol0 = n0 - D_OUT; }

    #pragma unroll
    for (int f = 0; f < 8; ++f)
        #pragma unroll
        for (int g = 0; g < 4; ++g) {
            int mrow = m0 + wr * 128 + f * 16 + quad * 4;  // row=(lane>>4)*4+reg
            int ncol = ncol0 + wc * 64 + g * 16 + r;       // col=lane&15
            #pragma unroll
            for (int reg = 0; reg < 4; ++reg)
                obase[(size_t)(mrow + reg) * D_OUT + ncol] = acc[f][g][reg] * scale;
        }
}

extern "C" void kernel_launch(void* const* d_in, const int* in_sizes, int n_in,
                              void* d_out, int out_size, void* d_ws, size_t ws_size,
                              hipStream_t stream) {
    const float* xr    = (const float*)d_in[0];
    const float* xi    = (const float*)d_in[1];
    const float* wre   = (const float*)d_in[2];
    const float* wim   = (const float*)d_in[3];
    const float* gamma = (const float*)d_in[4];
    const float* beta  = (const float*)d_in[5];
    float* out = (float*)d_out;

    // ws layout: A bf16 (GM*GK), W_cat bf16 (GN*GK), sums (2 f32)
    unsigned short* A  = (unsigned short*)d_ws;
    unsigned short* Wq = (unsigned short*)((char*)d_ws + (size_t)GM * GK * 2);
    float* sums = (float*)((char*)d_ws + (size_t)GM * GK * 2 + (size_t)GN * GK * 2);

    (void)hipMemsetAsync(sums, 0, 2 * sizeof(float), stream);
    quant_kernel<<<QB, 256, 0, stream>>>(wre, wim, Wq, sums);
    ln_kernel<<<GM, 256, 0, stream>>>(xr, xi, gamma, beta, A);
    gemm_kernel<<<dim3(GN / 256, GM / 256), 512, 0, stream>>>(A, Wq, sums, out);
}

// Round 3
// 528.148 us; speedup vs baseline: 1.1069x; 1.0717x over previous
//
#include <hip/hip_runtime.h>
#include <hip/hip_bf16.h>

// Problem constants (from setup_inputs): B=4, S=2048, D_IN=2048, D_OUT=2048
constexpr int D_IN  = 2048;
constexpr int D_OUT = 2048;
constexpr int GM = 4 * 2048;      // B*S rows
constexpr int GK = 2 * D_IN;      // 4096 (concat real|imag)
constexpr int GN = 2 * D_OUT;     // 4096 (concat y_real|y_imag channels)

typedef __attribute__((ext_vector_type(8))) short bf16x8;
typedef __attribute__((ext_vector_type(4))) float f32x4;

constexpr int QB = 1024;          // quant kernel blocks

// Exact bf16 bit patterns for {0, +-0.5, +-1}; negate = XOR 0x8000.
__device__ inline unsigned short q4bits(float w) {
    if (w >  0.75f) return 0x3F80;   // 1.0
    if (w >  0.25f) return 0x3F00;   // 0.5
    if (w < -0.75f) return 0xBF80;   // -1.0
    if (w < -0.25f) return 0xBF00;   // -0.5
    return 0;
}

__device__ inline unsigned short bf16b(float x) {
    __hip_bfloat16 h = __float2bfloat16(x);
    unsigned short u;
    __builtin_memcpy(&u, &h, 2);
    return u;
}

// ---------------------------------------------------------------------------
// Kernel 1: quantize weights into W_cat (bf16, GN x GK, row-major); block sums
// of |w_re|, |w_im| accumulated into sums[2] via device-scope atomics
// (sums zeroed by hipMemsetAsync before launch).
// W_cat row n<2048:  [ qre[n,:] | -qim[n,:] ]   -> y_real channels
// W_cat row n>=2048: [ qim[n,:] |  qre[n,:] ]   -> y_imag channels
// ---------------------------------------------------------------------------
__global__ __launch_bounds__(256) void quant_kernel(
        const float* __restrict__ wre, const float* __restrict__ wim,
        unsigned short* __restrict__ wq, float* __restrict__ sums) {
    float a = 0.f, b = 0.f;
    int tid = blockIdx.x * 256 + threadIdx.x;     // 0 .. 262143
    const float4* wre4 = (const float4*)wre;
    const float4* wim4 = (const float4*)wim;
    for (int c = 0; c < 4; c++) {
        int f4i = tid + c * (QB * 256);           // float4 index, coalesced
        int idx = f4i * 4;
        int o = idx >> 11;                        // row in D_OUT
        int k = idx & (D_IN - 1);                 // col in D_IN (multiple of 4)
        float4 r = wre4[f4i];
        float4 im = wim4[f4i];
        a += fabsf(r.x) + fabsf(r.y) + fabsf(r.z) + fabsf(r.w);
        b += fabsf(im.x) + fabsf(im.y) + fabsf(im.z) + fabsf(im.w);
        ushort4 qre, qim, nim;
        qre.x = q4bits(r.x);  qre.y = q4bits(r.y);  qre.z = q4bits(r.z);  qre.w = q4bits(r.w);
        qim.x = q4bits(im.x); qim.y = q4bits(im.y); qim.z = q4bits(im.z); qim.w = q4bits(im.w);
        nim.x = qim.x ^ 0x8000; nim.y = qim.y ^ 0x8000;
        nim.z = qim.z ^ 0x8000; nim.w = qim.w ^ 0x8000;
        *(ushort4*)(wq + (size_t)o * GK + k)                  = qre;
        *(ushort4*)(wq + (size_t)o * GK + D_IN + k)           = nim;
        *(ushort4*)(wq + (size_t)(D_OUT + o) * GK + k)        = qim;
        *(ushort4*)(wq + (size_t)(D_OUT + o) * GK + D_IN + k) = qre;
    }
    for (int off = 32; off; off >>= 1) {
        a += __shfl_down(a, off, 64);
        b += __shfl_down(b, off, 64);
    }
    __shared__ float sa[4], sb[4];
    int lane = threadIdx.x & 63, wv = threadIdx.x >> 6;
    if (lane == 0) { sa[wv] = a; sb[wv] = b; }
    __syncthreads();
    if (threadIdx.x == 0) {
        atomicAdd(&sums[0], sa[0] + sa[1] + sa[2] + sa[3]);
        atomicAdd(&sums[1], sb[0] + sb[1] + sb[2] + sb[3]);
    }
}

// ---------------------------------------------------------------------------
// Kernel 2: LayerNorm over concat row [x_real[m,:], x_imag[m,:]] (4096 elems),
// writes bf16 activations A (GM x GK row-major). One 256-thread block per row.
// ---------------------------------------------------------------------------
__global__ __launch_bounds__(256) void ln_kernel(
        const float* __restrict__ xr, const float* __restrict__ xi,
        const float* __restrict__ gamma, const float* __restrict__ beta,
        unsigned short* __restrict__ A) {
    int m = blockIdx.x;
    int t = threadIdx.x;
    const float4* r4 = (const float4*)(xr + (size_t)m * D_IN);
    const float4* i4 = (const float4*)(xi + (size_t)m * D_IN);
    float4 vr[2], vi[2];
    float s = 0.f, ss = 0.f;
    for (int c = 0; c < 2; c++) {
        float4 v = r4[t + c * 256];
        vr[c] = v;
        s  += v.x + v.y + v.z + v.w;
        ss += v.x * v.x + v.y * v.y + v.z * v.z + v.w * v.w;
        v = i4[t + c * 256];
        vi[c] = v;
        s  += v.x + v.y + v.z + v.w;
        ss += v.x * v.x + v.y * v.y + v.z * v.z + v.w * v.w;
    }
    for (int off = 32; off; off >>= 1) {
        s  += __shfl_down(s, off, 64);
        ss += __shfl_down(ss, off, 64);
    }
    __shared__ float red[8];
    __shared__ float smu, srs;
    int lane = t & 63, wv = t >> 6;
    if (lane == 0) { red[wv] = s; red[4 + wv] = ss; }
    __syncthreads();
    if (t == 0) {
        float S  = red[0] + red[1] + red[2] + red[3];
        float SS = red[4] + red[5] + red[6] + red[7];
        float mu  = S * (1.0f / 4096.0f);
        float var = SS * (1.0f / 4096.0f) - mu * mu;
        smu = mu;
        srs = rsqrtf(var + 1e-6f);
    }
    __syncthreads();
    float mu = smu, rs = srs;
    const float4* g4 = (const float4*)gamma;
    const float4* b4 = (const float4*)beta;
    ushort4* Arow = (ushort4*)(A + (size_t)m * GK);
    for (int c = 0; c < 2; c++) {
        int k4 = t + c * 256;                 // float4 index in real half
        float4 g = g4[k4], b = b4[k4];
        float4 v = vr[c];
        ushort4 o;
        o.x = bf16b((v.x - mu) * rs * g.x + b.x);
        o.y = bf16b((v.y - mu) * rs * g.y + b.y);
        o.z = bf16b((v.z - mu) * rs * g.z + b.z);
        o.w = bf16b((v.w - mu) * rs * g.w + b.w);
        Arow[k4] = o;
        g = g4[512 + k4]; b = b4[512 + k4];
        v = vi[c];
        o.x = bf16b((v.x - mu) * rs * g.x + b.x);
        o.y = bf16b((v.y - mu) * rs * g.y + b.y);
        o.z = bf16b((v.z - mu) * rs * g.z + b.z);
        o.w = bf16b((v.w - mu) * rs * g.w + b.w);
        Arow[512 + k4] = o;
    }
}

// ---------------------------------------------------------------------------
// Kernel 3: GEMM  Y(GM x GN) = A(GM x GK) * W_cat^T, W_cat stored N x K.
//
// Base = the verified 238us 128x128 kernel (BK=64, 4 waves, bf16 16x16x32
// MFMA, XOR-swizzled LDS, global_load_lds width-16, zero bank conflicts).
// Change vs that base: double-buffered LDS (2 x 32 KiB) with ONE-TILE
// prefetch slack and counted vmcnt:
//   - top of tile kt: issue all 8 global_load_lds for tile kt+1 into buf
//     nxt, then s_waitcnt vmcnt(8) -- waits only for tile kt's 8 loads
//     (issued one full tile, ~1000+ cy, earlier); kt+1's loads stay in
//     flight across the barrier. The old kernel issued loads with ZERO
//     slack then __syncthreads drained vmcnt(0): a full memory-latency
//     stall every K-tile (the measured 54%-util cap).
//   - raw s_barrier (never __syncthreads) so the compiler emits no
//     vmcnt(0) drain at barriers.
//   - explicit lgkmcnt(0) before the tile-end barrier: guarantees no
//     in-flight ds_read of buf cur when (after that barrier) the next
//     iteration's DMA starts overwriting it.
// LDS 64 KiB -> 2 blocks/CU (was 3): the bet is pipeline slack > the lost
// third block of cross-block overlap.
//
// Race safety: stages into buf nxt at top of kt overwrite the buffer last
// read during kt-1; all waves' ds_reads of it completed before kt-1's end
// barrier (explicit lgkmcnt(0) there), and stage issues sit after that
// barrier in program order (pinned by sched_barrier(0)), so the DMA writes
// land strictly after all reads. vmcnt(8) + s_barrier at kt's top ensures
// every wave's tile-kt loads landed before any wave reads them.
// ---------------------------------------------------------------------------
__global__ __launch_bounds__(256, 2) void gemm_kernel(
        const unsigned short* __restrict__ A,
        const unsigned short* __restrict__ Wq,
        const float* __restrict__ sums,
        float* __restrict__ out) {
    constexpr int BM = 128, BN = 128, BK = 64;
    constexpr int NT = GK / BK;                  // 64 K-tiles
    __shared__ unsigned short lsA[2][BM * BK];   // 2 x 16 KiB
    __shared__ unsigned short lsB[2][BN * BK];   // 2 x 16 KiB
    int n0 = blockIdx.x * BN;
    int m0 = blockIdx.y * BM;
    int t = threadIdx.x, lane = t & 63, wave = t >> 6;
    int wm = (wave >> 1) * 64;     // wave's m offset within tile
    int wn = (wave & 1) * 64;      // wave's n offset within tile
    int quad = lane >> 4, r = lane & 15;
    int srow = lane >> 3;                     // staging: row within 8-row group
    int scol = ((lane & 7) ^ srow) * 8;       // staging: swizzled bf16 col
    int csw0 = ((quad ^ (r & 7)) * 8);        // reader: elem offset, ks=0

    f32x4 acc[4][4] = {};

#define STAGE_TILE(bb, kk) do {                                                \
        for (int i_ = 0; i_ < 4; i_++) {                                       \
            int row_ = i_ * 32 + wave * 8;                                     \
            const unsigned short* gp_ =                                        \
                A + (size_t)(m0 + row_ + srow) * GK + (kk) * BK + scol;        \
            unsigned short* lp_ = lsA[bb] + row_ * BK;                         \
            __builtin_amdgcn_global_load_lds(                                  \
                (const __attribute__((address_space(1))) void*)(const void*)gp_,\
                (__attribute__((address_space(3))) void*)(void*)lp_, 16, 0, 0);\
        }                                                                      \
        for (int i_ = 0; i_ < 4; i_++) {                                       \
            int row_ = i_ * 32 + wave * 8;                                     \
            const unsigned short* gp_ =                                        \
                Wq + (size_t)(n0 + row_ + srow) * GK + (kk) * BK + scol;       \
            unsigned short* lp_ = lsB[bb] + row_ * BK;                         \
            __builtin_amdgcn_global_load_lds(                                  \
                (const __attribute__((address_space(1))) void*)(const void*)gp_,\
                (__attribute__((address_space(3))) void*)(void*)lp_, 16, 0, 0);\
        }                                                                      \
    } while (0)

    // Prologue: stage tile 0 into buf 0.
    STAGE_TILE(0, 0);

    #pragma unroll 2
    for (int kt = 0; kt < NT; ++kt) {
        int cur = kt & 1, nxt = cur ^ 1;

        // Issue next tile's loads first (full-tile slack), then counted wait.
        __builtin_amdgcn_sched_barrier(0);
        if (kt + 1 < NT) {
            STAGE_TILE(nxt, kt + 1);
            asm volatile("s_waitcnt vmcnt(8)" ::: "memory");   // tile kt landed
        } else {
            asm volatile("s_waitcnt vmcnt(0)" ::: "memory");
        }
        __builtin_amdgcn_s_barrier();        // all waves: tile kt visible
        __builtin_amdgcn_sched_barrier(0);

        const short* pa = (const short*)lsA[cur];
        const short* pb = (const short*)lsB[cur];
        for (int ks = 0; ks < 2; ks++) {
            bf16x8 af[4], bfr[4];
            int coff = csw0 ^ (ks * 32);
            for (int i = 0; i < 4; i++)
                af[i] = *(const bf16x8*)(pa + (wm + i * 16 + r) * BK + coff);
            for (int j = 0; j < 4; j++)
                bfr[j] = *(const bf16x8*)(pb + (wn + j * 16 + r) * BK + coff);
            for (int i = 0; i < 4; i++)
                for (int j = 0; j < 4; j++)
                    acc[i][j] = __builtin_amdgcn_mfma_f32_16x16x32_bf16(
                        af[i], bfr[j], acc[i][j], 0, 0, 0);
        }
        // Ensure this wave's LDS reads of buf cur are complete before the
        // tile-end barrier (after which buf cur may be overwritten by DMA).
        asm volatile("s_waitcnt lgkmcnt(0)" ::: "memory");
        __builtin_amdgcn_sched_barrier(0);
        __builtin_amdgcn_s_barrier();        // tile-end
    }
#undef STAGE_TILE

    // Epilogue: per-block uniform half selection (BN=128 divides D_OUT)
    float s_re = sums[0] * (1.0f / (2048.0f * 2048.0f));
    float s_im = sums[1] * (1.0f / (2048.0f * 2048.0f));
    float scale;
    float* obase;
    int ncol0;
    if (n0 < D_OUT) { scale = s_re; obase = out;                        ncol0 = n0; }
    else            { scale = s_im; obase = out + (size_t)GM * D_OUT;   ncol0 = n0 - D_OUT; }

    for (int i = 0; i < 4; i++)
        for (int j = 0; j < 4; j++) {
            int mrow = m0 + wm + i * 16 + quad * 4;   // C/D layout: row=(lane>>4)*4+reg
            int ncol = ncol0 + wn + j * 16 + r;       // col = lane&15
            for (int reg = 0; reg < 4; reg++)
                obase[(size_t)(mrow + reg) * D_OUT + ncol] = acc[i][j][reg] * scale;
        }
}

extern "C" void kernel_launch(void* const* d_in, const int* in_sizes, int n_in,
                              void* d_out, int out_size, void* d_ws, size_t ws_size,
                              hipStream_t stream) {
    const float* xr    = (const float*)d_in[0];
    const float* xi    = (const float*)d_in[1];
    const float* wre   = (const float*)d_in[2];
    const float* wim   = (const float*)d_in[3];
    const float* gamma = (const float*)d_in[4];
    const float* beta  = (const float*)d_in[5];
    float* out = (float*)d_out;

    // ws layout: A bf16 (GM*GK), W_cat bf16 (GN*GK), sums (2 f32)
    unsigned short* A  = (unsigned short*)d_ws;
    unsigned short* Wq = (unsigned short*)((char*)d_ws + (size_t)GM * GK * 2);
    float* sums = (float*)((char*)d_ws + (size_t)GM * GK * 2 + (size_t)GN * GK * 2);

    (void)hipMemsetAsync(sums, 0, 2 * sizeof(float), stream);
    quant_kernel<<<QB, 256, 0, stream>>>(wre, wim, Wq, sums);
    ln_kernel<<<GM, 256, 0, stream>>>(xr, xi, gamma, beta, A);
    gemm_kernel<<<dim3(GN / 128, GM / 128), 256, 0, stream>>>(A, Wq, sums, out);
}

// Round 4
// 478.745 us; speedup vs baseline: 1.2211x; 1.1032x over previous
//
#include <hip/hip_runtime.h>
#include <hip/hip_bf16.h>

// Problem constants (from setup_inputs): B=4, S=2048, D_IN=2048, D_OUT=2048
constexpr int D_IN  = 2048;
constexpr int D_OUT = 2048;
constexpr int GM = 4 * 2048;      // B*S rows
constexpr int GK = 2 * D_IN;      // 4096 (concat real|imag)
constexpr int GN = 2 * D_OUT;     // 4096 (concat y_real|y_imag channels)

typedef __attribute__((ext_vector_type(8))) short bf16x8;
typedef __attribute__((ext_vector_type(4))) float f32x4;

constexpr int QB = 1024;          // quant block count (tail of prep grid)

// Exact bf16 bit patterns for {0, +-0.5, +-1}; negate = XOR 0x8000.
__device__ inline unsigned short q4bits(float w) {
    if (w >  0.75f) return 0x3F80;   // 1.0
    if (w >  0.25f) return 0x3F00;   // 0.5
    if (w < -0.75f) return 0xBF80;   // -1.0
    if (w < -0.25f) return 0xBF00;   // -0.5
    return 0;
}

__device__ inline unsigned short bf16b(float x) {
    __hip_bfloat16 h = __float2bfloat16(x);
    unsigned short u;
    __builtin_memcpy(&u, &h, 2);
    return u;
}

// ---------------------------------------------------------------------------
// Fused prep kernel (grid-split):
//   blocks 0..GM-1      : LayerNorm of row m -> A (bf16, GM x GK)
//   blocks GM..GM+QB-1  : weight quantization -> W_cat (bf16, GN x GK) +
//                         per-block partial sums of |w_re|, |w_im|
// Both halves are the byte-identical bodies of the verified round-0 kernels;
// fusing removes one serialized launch boundary. No atomics, no memset.
//
// W_cat row n<2048:  [ qre[n,:] | -qim[n,:] ]   -> y_real channels
// W_cat row n>=2048: [ qim[n,:] |  qre[n,:] ]   -> y_imag channels
// ---------------------------------------------------------------------------
__global__ __launch_bounds__(256) void prep_kernel(
        const float* __restrict__ xr, const float* __restrict__ xi,
        const float* __restrict__ gamma, const float* __restrict__ beta,
        unsigned short* __restrict__ A,
        const float* __restrict__ wre, const float* __restrict__ wim,
        unsigned short* __restrict__ wq, float* __restrict__ partial) {
    __shared__ float red[8];
    __shared__ float smu, srs;

    if (blockIdx.x >= GM) {
        // ---------------- quant part ----------------
        int qb = blockIdx.x - GM;
        float a = 0.f, b = 0.f;
        int tid = qb * 256 + threadIdx.x;             // 0 .. 262143
        const float4* wre4 = (const float4*)wre;
        const float4* wim4 = (const float4*)wim;
        for (int c = 0; c < 4; c++) {
            int f4i = tid + c * (QB * 256);           // float4 index, coalesced
            int idx = f4i * 4;
            int o = idx >> 11;                        // row in D_OUT
            int k = idx & (D_IN - 1);                 // col in D_IN (mult of 4)
            float4 r = wre4[f4i];
            float4 im = wim4[f4i];
            a += fabsf(r.x) + fabsf(r.y) + fabsf(r.z) + fabsf(r.w);
            b += fabsf(im.x) + fabsf(im.y) + fabsf(im.z) + fabsf(im.w);
            ushort4 qre, qim, nim;
            qre.x = q4bits(r.x);  qre.y = q4bits(r.y);  qre.z = q4bits(r.z);  qre.w = q4bits(r.w);
            qim.x = q4bits(im.x); qim.y = q4bits(im.y); qim.z = q4bits(im.z); qim.w = q4bits(im.w);
            nim.x = qim.x ^ 0x8000; nim.y = qim.y ^ 0x8000;
            nim.z = qim.z ^ 0x8000; nim.w = qim.w ^ 0x8000;
            *(ushort4*)(wq + (size_t)o * GK + k)                  = qre;
            *(ushort4*)(wq + (size_t)o * GK + D_IN + k)           = nim;
            *(ushort4*)(wq + (size_t)(D_OUT + o) * GK + k)        = qim;
            *(ushort4*)(wq + (size_t)(D_OUT + o) * GK + D_IN + k) = qre;
        }
        for (int off = 32; off; off >>= 1) {
            a += __shfl_down(a, off, 64);
            b += __shfl_down(b, off, 64);
        }
        int lane = threadIdx.x & 63, wv = threadIdx.x >> 6;
        if (lane == 0) { red[wv] = a; red[4 + wv] = b; }
        __syncthreads();
        if (threadIdx.x == 0) {
            partial[qb]      = red[0] + red[1] + red[2] + red[3];
            partial[QB + qb] = red[4] + red[5] + red[6] + red[7];
        }
        return;
    }

    // ---------------- LayerNorm part ----------------
    int m = blockIdx.x;
    int t = threadIdx.x;
    const float4* r4 = (const float4*)(xr + (size_t)m * D_IN);
    const float4* i4 = (const float4*)(xi + (size_t)m * D_IN);
    float4 vr[2], vi[2];
    float s = 0.f, ss = 0.f;
    for (int c = 0; c < 2; c++) {
        float4 v = r4[t + c * 256];
        vr[c] = v;
        s  += v.x + v.y + v.z + v.w;
        ss += v.x * v.x + v.y * v.y + v.z * v.z + v.w * v.w;
        v = i4[t + c * 256];
        vi[c] = v;
        s  += v.x + v.y + v.z + v.w;
        ss += v.x * v.x + v.y * v.y + v.z * v.z + v.w * v.w;
    }
    for (int off = 32; off; off >>= 1) {
        s  += __shfl_down(s, off, 64);
        ss += __shfl_down(ss, off, 64);
    }
    int lane = t & 63, wv = t >> 6;
    if (lane == 0) { red[wv] = s; red[4 + wv] = ss; }
    __syncthreads();
    if (t == 0) {
        float S  = red[0] + red[1] + red[2] + red[3];
        float SS = red[4] + red[5] + red[6] + red[7];
        float mu  = S * (1.0f / 4096.0f);
        float var = SS * (1.0f / 4096.0f) - mu * mu;
        smu = mu;
        srs = rsqrtf(var + 1e-6f);
    }
    __syncthreads();
    float mu = smu, rs = srs;
    const float4* g4 = (const float4*)gamma;
    const float4* b4 = (const float4*)beta;
    ushort4* Arow = (ushort4*)(A + (size_t)m * GK);
    for (int c = 0; c < 2; c++) {
        int k4 = t + c * 256;                 // float4 index in real half
        float4 g = g4[k4], b = b4[k4];
        float4 v = vr[c];
        ushort4 o;
        o.x = bf16b((v.x - mu) * rs * g.x + b.x);
        o.y = bf16b((v.y - mu) * rs * g.y + b.y);
        o.z = bf16b((v.z - mu) * rs * g.z + b.z);
        o.w = bf16b((v.w - mu) * rs * g.w + b.w);
        Arow[k4] = o;
        g = g4[512 + k4]; b = b4[512 + k4];
        v = vi[c];
        o.x = bf16b((v.x - mu) * rs * g.x + b.x);
        o.y = bf16b((v.y - mu) * rs * g.y + b.y);
        o.z = bf16b((v.z - mu) * rs * g.z + b.z);
        o.w = bf16b((v.w - mu) * rs * g.w + b.w);
        Arow[512 + k4] = o;
    }
}

// ---------------------------------------------------------------------------
// Kernel 3: GEMM  Y(GM x GN) = A(GM x GK) * W_cat^T, W_cat stored N x K.
// BYTE-IDENTICAL to the verified 238us round-0 kernel (128x128 tile, BK=64,
// single-buffered LDS + __syncthreads drain, XOR-swizzled staging/readers,
// zero bank conflicts, 3 blocks/CU), except:
//   - a short prologue reduces partial[2*QB] (8 KB, L2-resident) into the
//     two scale factors in LDS, replacing the separate reduce kernel +
//     memset + atomics. Runs once, overlapped with the first tile stage.
// Three rounds of schedule surgery (256^2 4-phase, dbuf+counted-vmcnt) all
// regressed vs this structure (35%/42% vs 54% MfmaUtil) -- cross-block
// overlap at 3 blocks/CU beats intra-block pipelining here. Do not touch.
// ---------------------------------------------------------------------------
__global__ __launch_bounds__(256, 2) void gemm_kernel(
        const unsigned short* __restrict__ A,
        const unsigned short* __restrict__ Wq,
        const float* __restrict__ partial,
        float* __restrict__ out) {
    constexpr int BM = 128, BN = 128, BK = 64;
    __shared__ unsigned short lsA[BM * BK];
    __shared__ unsigned short lsB[BN * BK];
    __shared__ float sred[8];
    __shared__ float s_scale[2];
    int n0 = blockIdx.x * BN;
    int m0 = blockIdx.y * BM;
    int t = threadIdx.x, lane = t & 63, wave = t >> 6;
    int wm = (wave >> 1) * 64;     // wave's m offset within tile
    int wn = (wave & 1) * 64;      // wave's n offset within tile
    int quad = lane >> 4, r = lane & 15;
    int srow = lane >> 3;                     // staging: row within 8-row group
    int scol = ((lane & 7) ^ srow) * 8;       // staging: swizzled bf16 col
    int csw0 = ((quad ^ (r & 7)) * 8);        // reader: elem offset, ks=0

    // Prologue: reduce partial sums -> scale factors (once per block, cheap,
    // overlaps the first tile's staging latency).
    {
        float a = 0.f, b = 0.f;
        for (int i = t; i < QB; i += 256) { a += partial[i]; b += partial[QB + i]; }
        for (int off = 32; off; off >>= 1) {
            a += __shfl_down(a, off, 64);
            b += __shfl_down(b, off, 64);
        }
        if (lane == 0) { sred[wave] = a; sred[4 + wave] = b; }
        __syncthreads();
        if (t == 0) {
            s_scale[0] = (sred[0] + sred[1] + sred[2] + sred[3]) * (1.0f / (2048.0f * 2048.0f));
            s_scale[1] = (sred[4] + sred[5] + sred[6] + sred[7]) * (1.0f / (2048.0f * 2048.0f));
        }
        // no sync needed yet: first K-loop __syncthreads covers visibility
    }

    f32x4 acc[4][4] = {};

    for (int k0 = 0; k0 < GK; k0 += BK) {
        // stage A tile (128 rows x 64 cols bf16): 4 issues of 16B per thread
        for (int i = 0; i < 4; i++) {
            int row = i * 32 + wave * 8;
            const unsigned short* gp = A + (size_t)(m0 + row + srow) * GK + k0 + scol;
            unsigned short* lp = lsA + row * BK;   // wave-uniform LDS base
            __builtin_amdgcn_global_load_lds(
                (const __attribute__((address_space(1))) void*)(const void*)gp,
                (__attribute__((address_space(3))) void*)(void*)lp, 16, 0, 0);
        }
        // stage W tile (128 rows x 64 cols bf16)
        for (int i = 0; i < 4; i++) {
            int row = i * 32 + wave * 8;
            const unsigned short* gp = Wq + (size_t)(n0 + row + srow) * GK + k0 + scol;
            unsigned short* lp = lsB + row * BK;
            __builtin_amdgcn_global_load_lds(
                (const __attribute__((address_space(1))) void*)(const void*)gp,
                (__attribute__((address_space(3))) void*)(void*)lp, 16, 0, 0);
        }
        __syncthreads();
        for (int ks = 0; ks < 2; ks++) {
            bf16x8 af[4], bfr[4];
            const short* pa = (const short*)lsA;
            const short* pb = (const short*)lsB;
            int coff = csw0 ^ (ks * 32);
            for (int i = 0; i < 4; i++)
                af[i] = *(const bf16x8*)(pa + (wm + i * 16 + r) * BK + coff);
            for (int j = 0; j < 4; j++)
                bfr[j] = *(const bf16x8*)(pb + (wn + j * 16 + r) * BK + coff);
            for (int i = 0; i < 4; i++)
                for (int j = 0; j < 4; j++)
                    acc[i][j] = __builtin_amdgcn_mfma_f32_16x16x32_bf16(
                        af[i], bfr[j], acc[i][j], 0, 0, 0);
        }
        __syncthreads();
    }

    // Epilogue: per-block uniform half selection (BN=128 divides D_OUT)
    float scale;
    float* obase;
    int ncol0;
    if (n0 < D_OUT) { scale = s_scale[0]; obase = out;                      ncol0 = n0; }
    else            { scale = s_scale[1]; obase = out + (size_t)GM * D_OUT; ncol0 = n0 - D_OUT; }

    for (int i = 0; i < 4; i++)
        for (int j = 0; j < 4; j++) {
            int mrow = m0 + wm + i * 16 + quad * 4;   // C/D layout: row=(lane>>4)*4+reg
            int ncol = ncol0 + wn + j * 16 + r;       // col = lane&15
            for (int reg = 0; reg < 4; reg++)
                obase[(size_t)(mrow + reg) * D_OUT + ncol] = acc[i][j][reg] * scale;
        }
}

extern "C" void kernel_launch(void* const* d_in, const int* in_sizes, int n_in,
                              void* d_out, int out_size, void* d_ws, size_t ws_size,
                              hipStream_t stream) {
    const float* xr    = (const float*)d_in[0];
    const float* xi    = (const float*)d_in[1];
    const float* wre   = (const float*)d_in[2];
    const float* wim   = (const float*)d_in[3];
    const float* gamma = (const float*)d_in[4];
    const float* beta  = (const float*)d_in[5];
    float* out = (float*)d_out;

    // ws layout: A bf16 (GM*GK), W_cat bf16 (GN*GK), partial (2*QB f32)
    unsigned short* A  = (unsigned short*)d_ws;
    unsigned short* Wq = (unsigned short*)((char*)d_ws + (size_t)GM * GK * 2);
    float* partial = (float*)((char*)d_ws + (size_t)GM * GK * 2 + (size_t)GN * GK * 2);

    prep_kernel<<<GM + QB, 256, 0, stream>>>(xr, xi, gamma, beta, A,
                                             wre, wim, Wq, partial);
    gemm_kernel<<<dim3(GN / 128, GM / 128), 256, 0, stream>>>(A, Wq, partial, out);
}